// Round 6
// baseline (68.251 us; speedup 1.0000x reference)
//
#include <hip/hip_runtime.h>
#include <stdint.h>

// ChiSquareLoss: per-image RGB 256-bin histograms of two [B,3,512,512] f32
// tensors, normalized, chi-square over 768 bins, mean over batch.
//
// R4 design (byte-counter histogram, conflict-free fixed-bank layout), R5 fix:
// block decomposition was bid>>8 / bid&255 (÷256) instead of ÷384 -> 1/3 of
// blocks flushed to the wrong (or out-of-range) histogram. Fixed with exact
// integer division. Restored 0-clamp via med3.
//
// Design recap:
//  - scattered LDS atomics measured ~33 cyc/wave-instr (R0-R2 hist all ~43us,
//    layout-invariant) -> replaced by per-thread PRIVATE byte counters:
//    byte(tid,bin) at (tid<<2) + ((bin&0xFC)<<8) + (bin&3), i.e. word
//    (bin>>2)*256 + tid -> bank = tid&31, 2 lanes/bank = conflict-free.
//  - same-bin hazards within a float4 resolved by 6 compares (dedupe
//    increments; per-wave in-order DS pipe, last write carries the sum).
//  - 2 epochs x 128 elems/thread -> byte counters can never overflow.
//  - 64KB hist + 2KB stage = 66KB LDS -> 2 blocks/CU; grid 768 = 3 waves-
//    rounds... (2 resident + 1 queued per CU), each block = quarter-channel.

#define NCH       3
#define BINS      256
#define CBINS     (NCH * BINS)          // 768
#define THREADS   256
#define PAGES     64                    // 256 bins / 4 per page
#define HIST_WORDS (PAGES * THREADS)    // 16384 words = 64 KB
#define STAGE_WORDS (THREADS * 2)       // 512 words = 2 KB
#define LDS_BYTES ((HIST_WORDS + STAGE_WORDS) * 4)   // 67584 B
#define EPOCHS    2
#define BATCHES   4
#define BATCH     8                     // float4 per batch per thread
// per epoch: 4*8 = 32 f4/thread = 128 elems (<=128 per bin -> u8 safe)

__global__ __launch_bounds__(THREADS, 2)
void hist_kernel(const float* __restrict__ in0,
                 const float* __restrict__ in1,
                 unsigned int* __restrict__ ghist,   // [2][B][768]
                 int B) {
    extern __shared__ uint32_t lds[];               // [HIST | STAGE]
    uint32_t* const stage = lds + HIST_WORDS;
    unsigned char* const hb = (unsigned char*)lds;

    const int tid = threadIdx.x;
    const int bid = blockIdx.x;
    // grid 2*B*12: input (2) x img (B) x ch (3) x seg (4)  — exact division
    const int bpin  = B * 12;                   // blocks per input (384)
    const int input = bid / bpin;
    const int r     = bid - input * bpin;
    const int img   = r / 12;
    const int r2    = r - img * 12;
    const int ch    = r2 >> 2;
    const int seg   = r2 & 3;

    const float4* __restrict__ src = (const float4*)(input ? in1 : in0)
        + (size_t)img * 196608 + (size_t)ch * 65536 + (size_t)seg * 16384;

    const uint32_t hbase = (uint32_t)(tid << 2);

    for (int e = 0; e < EPOCHS; ++e) {
        // prefetch batch 0 before zeroing (vmcnt overlaps LDS zero)
        float4 va[BATCH], vb[BATCH];
        #pragma unroll
        for (int j = 0; j < BATCH; ++j)
            va[j] = src[(e * 32 + j) * THREADS + tid];

        // zero hist: 16384 words = 4096 uint4, 16 per thread
        #pragma unroll
        for (int k = 0; k < 16; ++k)
            ((uint4*)lds)[tid + k * THREADS] = make_uint4(0u, 0u, 0u, 0u);
        __syncthreads();

        #pragma unroll
        for (int b = 0; b < BATCHES; ++b) {
            float4* cur = (b & 1) ? vb : va;
            float4* nxt = (b & 1) ? va : vb;
            if (b < BATCHES - 1) {
                #pragma unroll
                for (int j = 0; j < BATCH; ++j)
                    nxt[j] = src[(e * 32 + (b + 1) * BATCH + j) * THREADS + tid];
            }
            #pragma unroll
            for (int q = 0; q < BATCH; ++q) {
                const float4 v = cur[q];
                // med3 clamp; truncation == floor for non-negative
                const uint32_t b0 = (uint32_t)fminf(fmaxf(v.x * 255.0f, 0.0f), 255.0f);
                const uint32_t b1 = (uint32_t)fminf(fmaxf(v.y * 255.0f, 0.0f), 255.0f);
                const uint32_t b2 = (uint32_t)fminf(fmaxf(v.z * 255.0f, 0.0f), 255.0f);
                const uint32_t b3 = (uint32_t)fminf(fmaxf(v.w * 255.0f, 0.0f), 255.0f);
                const uint32_t a0 = hbase + ((b0 & 0xFCu) << 8) + (b0 & 3u);
                const uint32_t a1 = hbase + ((b1 & 0xFCu) << 8) + (b1 & 3u);
                const uint32_t a2 = hbase + ((b2 & 0xFCu) << 8) + (b2 & 3u);
                const uint32_t a3 = hbase + ((b3 & 0xFCu) << 8) + (b3 & 3u);
                // reads issue before writes (may-alias preserved by compiler);
                // duplicate bins read the same stale value -> accumulate the
                // increment; in-order DS writes make the last write carry all.
                const uint32_t r0 = hb[a0];
                const uint32_t r1 = hb[a1];
                const uint32_t r2v = hb[a2];
                const uint32_t r3 = hb[a3];
                const uint32_t e1 = (b1 == b0);
                const uint32_t e2 = (uint32_t)(b2 == b0) + (uint32_t)(b2 == b1);
                const uint32_t e3 = (uint32_t)(b3 == b0) + (uint32_t)(b3 == b1) + (uint32_t)(b3 == b2);
                hb[a0] = (unsigned char)(r0 + 1u);
                hb[a1] = (unsigned char)(r1 + 1u + e1);
                hb[a2] = (unsigned char)(r2v + 1u + e2);
                hb[a3] = (unsigned char)(r3 + 1u + e3);
            }
        }
        __syncthreads();

        // flush phase 1: thread t sums page p = t>>2, row-quarter q = t&3.
        // rotation (j+tid)&63 keeps lanes on distinct banks (conflict-free).
        {
            const int p = tid >> 2, q = tid & 3;
            const uint32_t* pg = lds + p * THREADS + q * 64;
            uint32_t accE = 0, accO = 0;
            #pragma unroll 8
            for (int j = 0; j < 64; ++j) {
                const uint32_t x = pg[(j + tid) & 63];
                accE += x & 0x00FF00FFu;
                accO += (x >> 8) & 0x00FF00FFu;
            }
            stage[tid * 2]     = accE;   // u16: lo=bin 4p+0, hi=bin 4p+2
            stage[tid * 2 + 1] = accO;   // u16: lo=bin 4p+1, hi=bin 4p+3
        }
        __syncthreads();

        // flush phase 2: thread t = bin t; combine 4 quarter partials.
        {
            const int b   = tid;
            const int p2  = b >> 2;
            const int sel = b & 1;            // even bins in accE, odd in accO
            const int sh  = ((b >> 1) & 1) * 16;
            uint32_t sum = 0;
            #pragma unroll
            for (int qq = 0; qq < 4; ++qq)
                sum += (stage[(p2 * 4 + qq) * 2 + sel] >> sh) & 0xFFFFu;
            atomicAdd(&ghist[((size_t)(input * B + img) * NCH + ch) * BINS + b], sum);
        }
        // next epoch: zeroing touches hist only, phase2 touched stage only;
        // the post-zero __syncthreads orders stage reuse.
    }
}

__global__ __launch_bounds__(1024)
void chi_kernel(const unsigned int* __restrict__ ghist, float* __restrict__ out, int B) {
    const unsigned int* __restrict__ h1 = ghist;
    const unsigned int* __restrict__ h2 = ghist + (size_t)B * CBINS;
    const int total = B * CBINS;
    const float N = (float)(NCH * 512 * 512);   // 786432, exact per-image sum

    double acc = 0.0;
    for (int i = threadIdx.x; i < total; i += 1024) {
        float a1 = (float)h1[i] / N;
        float a2 = (float)h2[i] / N;
        float d = a1 - a2;
        float sm = a1 + a2 + 1e-10f;
        acc += (double)(d * d / sm);
    }

    #pragma unroll
    for (int off = 32; off > 0; off >>= 1)
        acc += __shfl_down(acc, off);

    __shared__ double wsum[16];
    if ((threadIdx.x & 63) == 0) wsum[threadIdx.x >> 6] = acc;
    __syncthreads();
    if (threadIdx.x == 0) {
        double t = 0.0;
        #pragma unroll
        for (int i = 0; i < 16; ++i) t += wsum[i];
        out[0] = (float)(t / (double)B);
    }
}

extern "C" void kernel_launch(void* const* d_in, const int* in_sizes, int n_in,
                              void* d_out, int out_size, void* d_ws, size_t ws_size,
                              hipStream_t stream) {
    const float* in0 = (const float*)d_in[0];
    const float* in1 = (const float*)d_in[1];
    const int B = in_sizes[0] / (NCH * 512 * 512);   // 32

    unsigned int* ghist = (unsigned int*)d_ws;
    const size_t hist_bytes = (size_t)2 * B * CBINS * sizeof(unsigned int);
    const int grid = 2 * B * 12;                     // 768

    hipMemsetAsync(d_ws, 0, hist_bytes, stream);
    hist_kernel<<<grid, THREADS, LDS_BYTES, stream>>>(in0, in1, ghist, B);
    chi_kernel<<<1, 1024, 0, stream>>>(ghist, (float*)d_out, B);
}

// Round 7
// 54.416 us; speedup vs baseline: 1.2542x; 1.2542x over previous
//
#include <hip/hip_runtime.h>
#include <stdint.h>

// ChiSquareLoss: per-image RGB 256-bin histograms of two [B,3,512,512] f32
// tensors, normalized, chi-square over 768 bins, mean over batch.
//
// R6: LDS-atomic throughput wall measured at 2 lanes/cyc (R0-R2: 98K cyc/CU,
// layout-invariant -> ~41us floor). Per-thread byte RMW (R5) beat the atomic
// THROUGHPUT but died on chain latency at 8 waves/CU (64KB LDS). This round:
// quad-shared u16 sub-histograms -> 33KB LDS -> 4 blocks/CU, 12+ waves.
//  - 64 sub-hists/block (one per 4-lane quad), 256 bins x u16, stride 33
//    words (+1 pad): RMW bank = (bin + g/2)&31 (scattered ~2-way, free),
//    flush bank = (bin + w)&31 (conflict-free).
//  - intra-quad same-bin races: symmetric dedupe. mov_dpp quad_perm gives
//    each lane its 3 mates' bins; inc = 1 + #matches. Matching lanes read
//    the same broadcast stale value and write IDENTICAL v+inc -> no lost
//    updates, no owner election, no suppression.
//  - cross-round RAW rides the per-wave in-order DS pipe (validated by R5:
//    absmax 0 with the same reliance). Compiler preserves DS order
//    (data-dependent indices -> may-alias).
//  - u16 max count = 4 lanes x 256 elems = 1024 << 65535: NO epochs; one
//    zero + one flush per block.

#define NCH       3
#define BINS      256
#define CBINS     (NCH * BINS)          // 768
#define THREADS   256
#define STRIDE_W  33                    // words per bin row: 32 data + 1 pad
#define HIST_WORDS (BINS * STRIDE_W)    // 8448 words = 33792 B
#define F4_PER_THREAD 64                // 256 elems/thread
#define CHUNK     4                     // float4 per prefetch chunk

__global__ __launch_bounds__(THREADS)
void hist_kernel(const float* __restrict__ in0,
                 const float* __restrict__ in1,
                 unsigned int* __restrict__ ghist,   // [2][B][768]
                 int B) {
    __shared__ uint32_t lh[HIST_WORDS];
    unsigned short* const lh16 = (unsigned short*)lh;

    const int tid = threadIdx.x;
    const int bid = blockIdx.x;
    // grid 2*B*12: input (2) x img (B) x ch (3) x seg (4)
    const int bpin  = B * 12;
    const int input = bid / bpin;
    const int r     = bid - input * bpin;
    const int img   = r / 12;
    const int r2    = r - img * 12;
    const int ch    = r2 >> 2;
    const int seg   = r2 & 3;

    const float4* __restrict__ src = (const float4*)(input ? in1 : in0)
        + (size_t)img * 196608 + (size_t)ch * 65536 + (size_t)seg * 16384;

    const uint32_t g = (uint32_t)(tid >> 2);   // quad id 0..63 -> sub-hist

    // prefetch chunk 0 before zeroing (vmcnt overlaps the LDS zero)
    float4 va[CHUNK], vb[CHUNK];
    #pragma unroll
    for (int j = 0; j < CHUNK; ++j) va[j] = src[j * THREADS + tid];

    // zero 8448 words = 2112 uint4 = 8/thread + 64-thread tail
    #pragma unroll
    for (int k = 0; k < 8; ++k)
        ((uint4*)lh)[tid + k * THREADS] = make_uint4(0u, 0u, 0u, 0u);
    if (tid < (HIST_WORDS / 4 - 8 * THREADS))
        ((uint4*)lh)[tid + 8 * THREADS] = make_uint4(0u, 0u, 0u, 0u);
    __syncthreads();

    #pragma unroll
    for (int c = 0; c < F4_PER_THREAD / CHUNK; ++c) {
        float4* cur = (c & 1) ? vb : va;
        float4* nxt = (c & 1) ? va : vb;
        if (c < F4_PER_THREAD / CHUNK - 1) {
            #pragma unroll
            for (int j = 0; j < CHUNK; ++j)
                nxt[j] = src[((c + 1) * CHUNK + j) * THREADS + tid];
        }
        #pragma unroll
        for (int q = 0; q < CHUNK; ++q) {
            const float4 v = cur[q];
            const float e[4] = {v.x, v.y, v.z, v.w};
            #pragma unroll
            for (int k = 0; k < 4; ++k) {
                // truncation == floor for non-negative; med3 clamp handles 1.0
                const uint32_t bin =
                    (uint32_t)fminf(fmaxf(e[k] * 255.0f, 0.0f), 255.0f);
                // mates' bins via quad_perm rotations {1,2,3,0},{2,3,0,1},{3,0,1,2}
                const uint32_t n1 = (uint32_t)__builtin_amdgcn_mov_dpp((int)bin, 0x39, 0xF, 0xF, true);
                const uint32_t n2 = (uint32_t)__builtin_amdgcn_mov_dpp((int)bin, 0x4E, 0xF, 0xF, true);
                const uint32_t n3 = (uint32_t)__builtin_amdgcn_mov_dpp((int)bin, 0x93, 0xF, 0xF, true);
                const uint32_t inc = 1u + (uint32_t)(bin == n1)
                                        + (uint32_t)(bin == n2)
                                        + (uint32_t)(bin == n3);
                const uint32_t idx = bin * (2u * STRIDE_W) + g;  // u16 index
                const uint32_t old = lh16[idx];
                lh16[idx] = (unsigned short)(old + inc);
            }
        }
    }
    __syncthreads();

    // flush: thread tid = bin tid; sum 64 u16 (32 words), bank (bin+w)&31
    {
        const uint32_t* row = lh + (uint32_t)tid * STRIDE_W;
        uint32_t sum = 0;
        #pragma unroll
        for (int w = 0; w < 32; ++w) {
            const uint32_t x = row[w];
            sum += (x & 0xFFFFu) + (x >> 16);
        }
        atomicAdd(&ghist[((size_t)(input * B + img) * NCH + ch) * BINS + tid], sum);
    }
}

__global__ __launch_bounds__(1024)
void chi_kernel(const unsigned int* __restrict__ ghist, float* __restrict__ out, int B) {
    const unsigned int* __restrict__ h1 = ghist;
    const unsigned int* __restrict__ h2 = ghist + (size_t)B * CBINS;
    const int total = B * CBINS;
    const float N = (float)(NCH * 512 * 512);   // 786432, exact per-image sum

    double acc = 0.0;
    for (int i = threadIdx.x; i < total; i += 1024) {
        float a1 = (float)h1[i] / N;
        float a2 = (float)h2[i] / N;
        float d = a1 - a2;
        float sm = a1 + a2 + 1e-10f;
        acc += (double)(d * d / sm);
    }

    #pragma unroll
    for (int off = 32; off > 0; off >>= 1)
        acc += __shfl_down(acc, off);

    __shared__ double wsum[16];
    if ((threadIdx.x & 63) == 0) wsum[threadIdx.x >> 6] = acc;
    __syncthreads();
    if (threadIdx.x == 0) {
        double t = 0.0;
        #pragma unroll
        for (int i = 0; i < 16; ++i) t += wsum[i];
        out[0] = (float)(t / (double)B);
    }
}

extern "C" void kernel_launch(void* const* d_in, const int* in_sizes, int n_in,
                              void* d_out, int out_size, void* d_ws, size_t ws_size,
                              hipStream_t stream) {
    const float* in0 = (const float*)d_in[0];
    const float* in1 = (const float*)d_in[1];
    const int B = in_sizes[0] / (NCH * 512 * 512);   // 32

    unsigned int* ghist = (unsigned int*)d_ws;
    const size_t hist_bytes = (size_t)2 * B * CBINS * sizeof(unsigned int);
    const int grid = 2 * B * 12;                     // 768

    hipMemsetAsync(d_ws, 0, hist_bytes, stream);
    hist_kernel<<<grid, THREADS, 0, stream>>>(in0, in1, ghist, B);
    chi_kernel<<<1, 1024, 0, stream>>>(ghist, (float*)d_out, B);
}